// Round 1
// baseline (110.187 us; speedup 1.0000x reference)
//
#include <hip/hip_runtime.h>
#include <hip/hip_bf16.h>

typedef __attribute__((ext_vector_type(8))) short bf16x8;
typedef __attribute__((ext_vector_type(8))) unsigned short u16x8;
typedef __attribute__((ext_vector_type(4))) float f32x4;

#define NEG_INF (-__builtin_inff())

static __device__ __forceinline__ unsigned short f2bf(float x) {
  union { float f; unsigned u; } v; v.f = x;
  unsigned r = (v.u + 0x7fffu + ((v.u >> 16) & 1u)) >> 16;
  return (unsigned short)r;
}

// ---- segment boundaries from sorted kv coors: seg[b]=start, seg[8+b]=end ----
__global__ void segments_kernel(const int* __restrict__ kvc, int n, int* __restrict__ seg) {
  int i = blockIdx.x * blockDim.x + threadIdx.x;
  int stride = gridDim.x * blockDim.x;
  for (; i < n; i += stride) {
    int c = kvc[i];
    int cp = (i == 0) ? -1 : kvc[i - 1];
    if (c != cp) {
      for (int b = cp + 1; b <= c; ++b) seg[b] = i;          // starts (incl. empties)
      if (i == 0) for (int b = 0; b < c; ++b) seg[8 + b] = 0; // leading empties end=0
    }
    int cn = (i == n - 1) ? 8 : kvc[i + 1];
    if (c != cn) {
      for (int b = c; b < cn; ++b) seg[8 + b] = i + 1;       // ends (incl. empties)
      if (i == n - 1) for (int b = c + 1; b < 8; ++b) seg[b] = n; // trailing starts=n
    }
  }
}

// ---- Q f32 -> bf16 row-major ----
__global__ void cvt_q_kernel(const float* __restrict__ q, unsigned short* __restrict__ qb, int n) {
  int i = (blockIdx.x * blockDim.x + threadIdx.x) * 8;
  if (i >= n) return;
  const float4* p = (const float4*)(q + i);
  float4 a = p[0], b = p[1];
  u16x8 v;
  v[0] = f2bf(a.x); v[1] = f2bf(a.y); v[2] = f2bf(a.z); v[3] = f2bf(a.w);
  v[4] = f2bf(b.x); v[5] = f2bf(b.y); v[6] = f2bf(b.z); v[7] = f2bf(b.w);
  *(u16x8*)(qb + i) = v;
}

// ---- KV f32 -> bf16 row-major AND bf16 transposed [64][nkv] ----
__global__ void prep_kv_kernel(const float* __restrict__ kv, unsigned short* __restrict__ kvb,
                               unsigned short* __restrict__ kvt, int nkv) {
  __shared__ unsigned short tile[32][64];
  int kv0 = blockIdx.x * 32;
  int t = threadIdx.x;              // 0..255; 8 elems each over 32x64 tile
  int r = (t * 8) >> 6;             // local kv row 0..31
  int c = (t * 8) & 63;             // feature
  const float4* src = (const float4*)(kv + (size_t)(kv0 + r) * 64 + c);
  float4 a = src[0], b = src[1];
  u16x8 v;
  v[0] = f2bf(a.x); v[1] = f2bf(a.y); v[2] = f2bf(a.z); v[3] = f2bf(a.w);
  v[4] = f2bf(b.x); v[5] = f2bf(b.y); v[6] = f2bf(b.z); v[7] = f2bf(b.w);
  *(u16x8*)&tile[r][c] = v;
  *(u16x8*)(kvb + (size_t)(kv0 + r) * 64 + c) = v;
  __syncthreads();
  int d = t & 63;                   // feature row of KV_T
  int k0 = (t >> 6) * 8;            // kv chunk 0/8/16/24
  u16x8 w;
#pragma unroll
  for (int j = 0; j < 8; ++j) w[j] = tile[k0 + j][d];
  *(u16x8*)(kvt + (size_t)d * nkv + kv0 + k0) = w;
}

// ---- main: one wave per 16-query tile, flash attention over its batch segment ----
__global__ __launch_bounds__(64) void attn_kernel(
    const unsigned short* __restrict__ qb,   // [n1][64] bf16
    const unsigned short* __restrict__ kvb,  // [n2][64] bf16
    const unsigned short* __restrict__ kvt,  // [64][n2] bf16
    const int* __restrict__ qc, const int* __restrict__ kvc,
    const int* __restrict__ seg,
    float* __restrict__ out, int n2)
{
  __shared__ float p_lds[16][36];            // padded: 2-way (free) banks, 16B-aligned rows
  const int q0 = blockIdx.x * 16;
  const int lane = threadIdx.x;
  const int q16 = lane & 15;
  const int g = lane >> 4;

  // Q A-fragments: A[i=lane&15][k=32*kb + 8*g + j]
  bf16x8 aq0 = *(const bf16x8*)(qb + (size_t)(q0 + q16) * 64 + g * 8);
  bf16x8 aq1 = *(const bf16x8*)(qb + (size_t)(q0 + q16) * 64 + 32 + g * 8);

  int qcoor[4];
#pragma unroll
  for (int r = 0; r < 4; ++r) qcoor[r] = qc[q0 + g * 4 + r];

  const int bfirst = qc[q0];
  const int blast  = qc[q0 + 15];
  const int kv_lo = seg[bfirst];
  const int kv_hi = seg[8 + blast];

  f32x4 acc0 = {0,0,0,0}, acc1 = {0,0,0,0}, acc2 = {0,0,0,0}, acc3 = {0,0,0,0};
  float m[4] = {NEG_INF, NEG_INF, NEG_INF, NEG_INF};
  float l[4] = {0, 0, 0, 0};
  const float scale = 0.125f;  // 1/sqrt(64)

  for (int kv0 = (kv_lo & ~31); kv0 < kv_hi; kv0 += 32) {
    // QK^T B-fragments: B[k][j=lane&15] = KV[kv0+sub*16+j][k], k = 32*kb + 8*g + jj
    const unsigned short* kr0 = kvb + (size_t)(kv0 + q16) * 64 + g * 8;
    const unsigned short* kr1 = kvb + (size_t)(kv0 + 16 + q16) * 64 + g * 8;
    bf16x8 b00 = *(const bf16x8*)(kr0);
    bf16x8 b01 = *(const bf16x8*)(kr0 + 32);
    bf16x8 b10 = *(const bf16x8*)(kr1);
    bf16x8 b11 = *(const bf16x8*)(kr1 + 32);
    const int kvc0 = kvc[kv0 + q16];
    const int kvc1 = kvc[kv0 + 16 + q16];

    f32x4 s0 = {0,0,0,0}, s1 = {0,0,0,0};
    s0 = __builtin_amdgcn_mfma_f32_16x16x32_bf16(aq0, b00, s0, 0, 0, 0);
    s0 = __builtin_amdgcn_mfma_f32_16x16x32_bf16(aq1, b01, s0, 0, 0, 0);
    s1 = __builtin_amdgcn_mfma_f32_16x16x32_bf16(aq0, b10, s1, 0, 0, 0);
    s1 = __builtin_amdgcn_mfma_f32_16x16x32_bf16(aq1, b11, s1, 0, 0, 0);

    float p0[4], p1[4], fr[4];
#pragma unroll
    for (int r = 0; r < 4; ++r) {
      float v0 = (qcoor[r] == kvc0) ? s0[r] * scale : NEG_INF;
      float v1 = (qcoor[r] == kvc1) ? s1[r] * scale : NEG_INF;
      float t = fmaxf(v0, v1);
      t = fmaxf(t, __shfl_xor(t, 1));
      t = fmaxf(t, __shfl_xor(t, 2));
      t = fmaxf(t, __shfl_xor(t, 4));
      t = fmaxf(t, __shfl_xor(t, 8));
      float mn = fmaxf(m[r], t);
      float f, e0, e1;
      if (mn == NEG_INF) { f = 1.0f; e0 = 0.0f; e1 = 0.0f; }
      else {
        f  = __expf(m[r] - mn);
        e0 = __expf(v0 - mn);
        e1 = __expf(v1 - mn);
      }
      float sm = e0 + e1;
      sm += __shfl_xor(sm, 1);
      sm += __shfl_xor(sm, 2);
      sm += __shfl_xor(sm, 4);
      sm += __shfl_xor(sm, 8);
      l[r] = l[r] * f + sm;
      m[r] = mn;
      p0[r] = e0; p1[r] = e1; fr[r] = f;
    }
#pragma unroll
    for (int r = 0; r < 4; ++r) {
      acc0[r] *= fr[r]; acc1[r] *= fr[r]; acc2[r] *= fr[r]; acc3[r] *= fr[r];
    }
    // P (16x32, f32) through LDS: write D-layout, read A-layout (same wave, no barrier)
#pragma unroll
    for (int r = 0; r < 4; ++r) {
      p_lds[g * 4 + r][q16] = p0[r];
      p_lds[g * 4 + r][16 + q16] = p1[r];
    }
    float pv[8];
    *(f32x4*)&pv[0] = *(const f32x4*)&p_lds[q16][g * 8];
    *(f32x4*)&pv[4] = *(const f32x4*)&p_lds[q16][g * 8 + 4];
    bf16x8 pa;
#pragma unroll
    for (int j = 0; j < 8; ++j) pa[j] = (short)f2bf(pv[j]);

    // PV B-fragments from KV_T: B[k=8g+jj][j=lane&15] = KV_T[dt*16+j][kv0+8g+jj]
    const unsigned short* vt = kvt + kv0 + g * 8;
    bf16x8 bv0 = *(const bf16x8*)(vt + (size_t)(0 * 16 + q16) * n2);
    bf16x8 bv1 = *(const bf16x8*)(vt + (size_t)(1 * 16 + q16) * n2);
    bf16x8 bv2 = *(const bf16x8*)(vt + (size_t)(2 * 16 + q16) * n2);
    bf16x8 bv3 = *(const bf16x8*)(vt + (size_t)(3 * 16 + q16) * n2);
    acc0 = __builtin_amdgcn_mfma_f32_16x16x32_bf16(pa, bv0, acc0, 0, 0, 0);
    acc1 = __builtin_amdgcn_mfma_f32_16x16x32_bf16(pa, bv1, acc1, 0, 0, 0);
    acc2 = __builtin_amdgcn_mfma_f32_16x16x32_bf16(pa, bv2, acc2, 0, 0, 0);
    acc3 = __builtin_amdgcn_mfma_f32_16x16x32_bf16(pa, bv3, acc3, 0, 0, 0);
  }

  float inv[4];
#pragma unroll
  for (int r = 0; r < 4; ++r) inv[r] = (l[r] > 0.0f) ? 1.0f / l[r] : 0.0f;
#pragma unroll
  for (int r = 0; r < 4; ++r) {
    float* o = out + (size_t)(q0 + g * 4 + r) * 64 + q16;
    o[0]  = acc0[r] * inv[r];
    o[16] = acc1[r] * inv[r];
    o[32] = acc2[r] * inv[r];
    o[48] = acc3[r] * inv[r];
  }
}

extern "C" void kernel_launch(void* const* d_in, const int* in_sizes, int n_in,
                              void* d_out, int out_size, void* d_ws, size_t ws_size,
                              hipStream_t stream) {
  const float* q  = (const float*)d_in[0];
  const float* kv = (const float*)d_in[1];
  const int* qc   = (const int*)d_in[2];
  const int* kvc  = (const int*)d_in[3];
  float* out = (float*)d_out;

  const int C = 64;
  const int n1 = in_sizes[0] / C;   // 8192
  const int n2 = in_sizes[1] / C;   // 8192

  char* ws = (char*)d_ws;
  size_t off = 0;
  unsigned short* qb  = (unsigned short*)(ws + off); off += (size_t)n1 * C * 2;
  unsigned short* kvb = (unsigned short*)(ws + off); off += (size_t)n2 * C * 2;
  unsigned short* kvt = (unsigned short*)(ws + off); off += (size_t)n2 * C * 2;
  int* seg = (int*)(ws + off);

  segments_kernel<<<32, 256, 0, stream>>>(kvc, n2, seg);
  cvt_q_kernel<<<(n1 * C / 8 + 255) / 256, 256, 0, stream>>>(q, qb, n1 * C);
  prep_kv_kernel<<<n2 / 32, 256, 0, stream>>>(kv, kvb, kvt, n2);
  attn_kernel<<<n1 / 16, 64, 0, stream>>>(qb, kvb, kvt, qc, kvc, seg, out, n2);
}

// Round 2
// 50.077 us; speedup vs baseline: 2.2004x; 2.2004x over previous
//
#include <hip/hip_runtime.h>
#include <hip/hip_bf16.h>

typedef __attribute__((ext_vector_type(8))) short bf16x8;
typedef __attribute__((ext_vector_type(8))) unsigned short u16x8;
typedef __attribute__((ext_vector_type(4))) float f32x4;

#define NEG_INF (-__builtin_inff())
#define SPLIT 4

static __device__ __forceinline__ unsigned short f2bf(float x) {
  union { float f; unsigned u; } v; v.f = x;
  unsigned r = (v.u + 0x7fffu + ((v.u >> 16) & 1u)) >> 16;
  return (unsigned short)r;
}

// ---- segment boundaries from sorted kv coors: seg[b]=start, seg[8+b]=end ----
__global__ void segments_kernel(const int* __restrict__ kvc, int n, int* __restrict__ seg) {
  int i = blockIdx.x * blockDim.x + threadIdx.x;
  int stride = gridDim.x * blockDim.x;
  for (; i < n; i += stride) {
    int c = kvc[i];
    int cp = (i == 0) ? -1 : kvc[i - 1];
    if (c != cp) {
      for (int b = cp + 1; b <= c; ++b) seg[b] = i;
      if (i == 0) for (int b = 0; b < c; ++b) seg[8 + b] = 0;
    }
    int cn = (i == n - 1) ? 8 : kvc[i + 1];
    if (c != cn) {
      for (int b = c; b < cn; ++b) seg[8 + b] = i + 1;
      if (i == n - 1) for (int b = c + 1; b < 8; ++b) seg[b] = n;
    }
  }
}

// ---- KV f32 -> bf16 row-major AND bf16 transposed [64][nkv] ----
__global__ void prep_kv_kernel(const float* __restrict__ kv, unsigned short* __restrict__ kvb,
                               unsigned short* __restrict__ kvt, int nkv) {
  __shared__ unsigned short tile[32][64];
  int kv0 = blockIdx.x * 32;
  int t = threadIdx.x;
  int r = (t * 8) >> 6;
  int c = (t * 8) & 63;
  const float4* src = (const float4*)(kv + (size_t)(kv0 + r) * 64 + c);
  float4 a = src[0], b = src[1];
  u16x8 v;
  v[0] = f2bf(a.x); v[1] = f2bf(a.y); v[2] = f2bf(a.z); v[3] = f2bf(a.w);
  v[4] = f2bf(b.x); v[5] = f2bf(b.y); v[6] = f2bf(b.z); v[7] = f2bf(b.w);
  *(u16x8*)&tile[r][c] = v;
  *(u16x8*)(kvb + (size_t)(kv0 + r) * 64 + c) = v;
  __syncthreads();
  int d = t & 63;
  int k0 = (t >> 6) * 8;
  u16x8 w;
#pragma unroll
  for (int j = 0; j < 8; ++j) w[j] = tile[k0 + j][d];
  *(u16x8*)(kvt + (size_t)d * nkv + kv0 + k0) = w;
}

// ---- main: 4 waves per 16-query tile; each wave takes 1/4 of the KV segment ----
__global__ __launch_bounds__(256) void attn_kernel(
    const float* __restrict__ qf,            // [n1][64] f32
    const unsigned short* __restrict__ kvb,  // [n2][64] bf16
    const unsigned short* __restrict__ kvt,  // [64][n2] bf16
    const int* __restrict__ qc, const int* __restrict__ kvc,
    const int* __restrict__ seg,
    float* __restrict__ out, int n2)
{
  __shared__ float p_lds[SPLIT][16][36];
  __shared__ float macc[SPLIT][16][64];
  __shared__ float mml[SPLIT][16];
  __shared__ float mll[SPLIT][16];

  const int q0 = blockIdx.x * 16;
  const int w = threadIdx.x >> 6;
  const int lane = threadIdx.x & 63;
  const int q16 = lane & 15;
  const int g = lane >> 4;

  // Q A-fragments straight from f32: A[i=q16][k=32*kb + 8*g + j]
  bf16x8 aq0, aq1;
  {
    const float* qrow = qf + (size_t)(q0 + q16) * 64 + g * 8;
    float4 x0 = *(const float4*)(qrow);
    float4 x1 = *(const float4*)(qrow + 4);
    float4 x2 = *(const float4*)(qrow + 32);
    float4 x3 = *(const float4*)(qrow + 36);
    aq0[0]=(short)f2bf(x0.x); aq0[1]=(short)f2bf(x0.y); aq0[2]=(short)f2bf(x0.z); aq0[3]=(short)f2bf(x0.w);
    aq0[4]=(short)f2bf(x1.x); aq0[5]=(short)f2bf(x1.y); aq0[6]=(short)f2bf(x1.z); aq0[7]=(short)f2bf(x1.w);
    aq1[0]=(short)f2bf(x2.x); aq1[1]=(short)f2bf(x2.y); aq1[2]=(short)f2bf(x2.z); aq1[3]=(short)f2bf(x2.w);
    aq1[4]=(short)f2bf(x3.x); aq1[5]=(short)f2bf(x3.y); aq1[6]=(short)f2bf(x3.z); aq1[7]=(short)f2bf(x3.w);
  }

  int qcoor[4];
#pragma unroll
  for (int r = 0; r < 4; ++r) qcoor[r] = qc[q0 + g * 4 + r];

  const int bfirst = qc[q0];
  const int blast  = qc[q0 + 15];
  const int kv_lo = seg[bfirst];
  const int kv_hi = seg[8 + blast];
  const bool uniformb = (bfirst == blast);
  const int base = kv_lo & ~31;
  const int nblk = (kv_hi - base + 31) >> 5;
  const int b0 = (nblk * w) / SPLIT;
  const int b1 = (nblk * (w + 1)) / SPLIT;

  f32x4 acc0 = {0,0,0,0}, acc1 = {0,0,0,0}, acc2 = {0,0,0,0}, acc3 = {0,0,0,0};
  float m[4] = {NEG_INF, NEG_INF, NEG_INF, NEG_INF};
  float l[4] = {0, 0, 0, 0};   // per-lane partial sums (deferred reduce)
  const float scale = 0.125f;  // 1/sqrt(64)

  for (int b = b0; b < b1; ++b) {
    const int kv0 = base + b * 32;
    const unsigned short* kr0 = kvb + (size_t)(kv0 + q16) * 64 + g * 8;
    const unsigned short* kr1 = kvb + (size_t)(kv0 + 16 + q16) * 64 + g * 8;
    bf16x8 bk00 = *(const bf16x8*)(kr0);
    bf16x8 bk01 = *(const bf16x8*)(kr0 + 32);
    bf16x8 bk10 = *(const bf16x8*)(kr1);
    bf16x8 bk11 = *(const bf16x8*)(kr1 + 32);

    f32x4 s0 = {0,0,0,0}, s1 = {0,0,0,0};
    s0 = __builtin_amdgcn_mfma_f32_16x16x32_bf16(aq0, bk00, s0, 0, 0, 0);
    s0 = __builtin_amdgcn_mfma_f32_16x16x32_bf16(aq1, bk01, s0, 0, 0, 0);
    s1 = __builtin_amdgcn_mfma_f32_16x16x32_bf16(aq0, bk10, s1, 0, 0, 0);
    s1 = __builtin_amdgcn_mfma_f32_16x16x32_bf16(aq1, bk11, s1, 0, 0, 0);

    const bool full = uniformb && (kv0 >= kv_lo) && (kv0 + 32 <= kv_hi);
    float v0[4], v1[4];
    if (full) {
#pragma unroll
      for (int r = 0; r < 4; ++r) { v0[r] = s0[r] * scale; v1[r] = s1[r] * scale; }
    } else {
      const int kvc0 = kvc[kv0 + q16];
      const int kvc1 = kvc[kv0 + 16 + q16];
#pragma unroll
      for (int r = 0; r < 4; ++r) {
        v0[r] = (qcoor[r] == kvc0) ? s0[r] * scale : NEG_INF;
        v1[r] = (qcoor[r] == kvc1) ? s1[r] * scale : NEG_INF;
      }
    }

    float p0[4], p1[4], fr[4];
#pragma unroll
    for (int r = 0; r < 4; ++r) {
      float t = fmaxf(v0[r], v1[r]);
      t = fmaxf(t, __shfl_xor(t, 1));
      t = fmaxf(t, __shfl_xor(t, 2));
      t = fmaxf(t, __shfl_xor(t, 4));
      t = fmaxf(t, __shfl_xor(t, 8));
      float mn = fmaxf(m[r], t);
      float f, e0, e1;
      if (mn == NEG_INF) { f = 1.0f; e0 = 0.0f; e1 = 0.0f; }
      else {
        f  = __expf(m[r] - mn);
        e0 = __expf(v0[r] - mn);
        e1 = __expf(v1[r] - mn);
      }
      l[r] = l[r] * f + e0 + e1;
      m[r] = mn;
      p0[r] = e0; p1[r] = e1; fr[r] = f;
    }
#pragma unroll
    for (int r = 0; r < 4; ++r) {
      acc0[r] *= fr[r]; acc1[r] *= fr[r]; acc2[r] *= fr[r]; acc3[r] *= fr[r];
    }
    // P (16x32 f32) through LDS: write D-layout, read A-layout (same wave, no barrier)
#pragma unroll
    for (int r = 0; r < 4; ++r) {
      p_lds[w][g * 4 + r][q16] = p0[r];
      p_lds[w][g * 4 + r][16 + q16] = p1[r];
    }
    float pv[8];
    *(f32x4*)&pv[0] = *(const f32x4*)&p_lds[w][q16][g * 8];
    *(f32x4*)&pv[4] = *(const f32x4*)&p_lds[w][q16][g * 8 + 4];
    bf16x8 pa;
#pragma unroll
    for (int j = 0; j < 8; ++j) pa[j] = (short)f2bf(pv[j]);

    const unsigned short* vt = kvt + kv0 + g * 8;
    bf16x8 bv0 = *(const bf16x8*)(vt + (size_t)(0 * 16 + q16) * n2);
    bf16x8 bv1 = *(const bf16x8*)(vt + (size_t)(1 * 16 + q16) * n2);
    bf16x8 bv2 = *(const bf16x8*)(vt + (size_t)(2 * 16 + q16) * n2);
    bf16x8 bv3 = *(const bf16x8*)(vt + (size_t)(3 * 16 + q16) * n2);
    acc0 = __builtin_amdgcn_mfma_f32_16x16x32_bf16(pa, bv0, acc0, 0, 0, 0);
    acc1 = __builtin_amdgcn_mfma_f32_16x16x32_bf16(pa, bv1, acc1, 0, 0, 0);
    acc2 = __builtin_amdgcn_mfma_f32_16x16x32_bf16(pa, bv2, acc2, 0, 0, 0);
    acc3 = __builtin_amdgcn_mfma_f32_16x16x32_bf16(pa, bv3, acc3, 0, 0, 0);
  }

  // finalize per-wave partials: reduce per-lane l across the 16-lane group
  float lsum[4];
#pragma unroll
  for (int r = 0; r < 4; ++r) {
    float sm = l[r];
    sm += __shfl_xor(sm, 1);
    sm += __shfl_xor(sm, 2);
    sm += __shfl_xor(sm, 4);
    sm += __shfl_xor(sm, 8);
    lsum[r] = sm;
  }
#pragma unroll
  for (int r = 0; r < 4; ++r) {
    const int row = g * 4 + r;
    macc[w][row][q16]      = acc0[r];
    macc[w][row][16 + q16] = acc1[r];
    macc[w][row][32 + q16] = acc2[r];
    macc[w][row][48 + q16] = acc3[r];
    if (q16 == 0) { mml[w][row] = m[r]; mll[w][row] = lsum[r]; }
  }
  __syncthreads();

  // merge SPLIT partials: 256 threads over 16 rows x 64 features
  {
    const int t = threadIdx.x;
    const int i = t >> 4;
    const int c0 = (t & 15) * 4;
    float mstar = NEG_INF;
#pragma unroll
    for (int ww = 0; ww < SPLIT; ++ww) mstar = fmaxf(mstar, mml[ww][i]);
    float s[SPLIT];
    float L = 0.0f;
#pragma unroll
    for (int ww = 0; ww < SPLIT; ++ww) {
      float mw = mml[ww][i];
      s[ww] = (mw == NEG_INF) ? 0.0f : __expf(mw - mstar);
      L += s[ww] * mll[ww][i];
    }
    float inv = (L > 0.0f) ? 1.0f / L : 0.0f;
    f32x4 num = {0,0,0,0};
#pragma unroll
    for (int ww = 0; ww < SPLIT; ++ww) {
      f32x4 a = *(const f32x4*)&macc[ww][i][c0];
      num[0] += s[ww] * a[0]; num[1] += s[ww] * a[1];
      num[2] += s[ww] * a[2]; num[3] += s[ww] * a[3];
    }
    float* o = out + (size_t)(q0 + i) * 64 + c0;
    o[0] = num[0] * inv; o[1] = num[1] * inv; o[2] = num[2] * inv; o[3] = num[3] * inv;
  }
}

extern "C" void kernel_launch(void* const* d_in, const int* in_sizes, int n_in,
                              void* d_out, int out_size, void* d_ws, size_t ws_size,
                              hipStream_t stream) {
  const float* q  = (const float*)d_in[0];
  const float* kv = (const float*)d_in[1];
  const int* qc   = (const int*)d_in[2];
  const int* kvc  = (const int*)d_in[3];
  float* out = (float*)d_out;

  const int C = 64;
  const int n1 = in_sizes[0] / C;   // 8192
  const int n2 = in_sizes[1] / C;   // 8192

  char* ws = (char*)d_ws;
  size_t off = 0;
  unsigned short* kvb = (unsigned short*)(ws + off); off += (size_t)n2 * C * 2;
  unsigned short* kvt = (unsigned short*)(ws + off); off += (size_t)n2 * C * 2;
  int* seg = (int*)(ws + off);

  segments_kernel<<<32, 256, 0, stream>>>(kvc, n2, seg);
  prep_kv_kernel<<<n2 / 32, 256, 0, stream>>>(kv, kvb, kvt, n2);
  attn_kernel<<<n1 / 16, 256, 0, stream>>>(q, kvb, kvt, qc, kvc, seg, out, n2);
}

// Round 3
// 36.347 us; speedup vs baseline: 3.0315x; 1.3777x over previous
//
#include <hip/hip_runtime.h>
#include <hip/hip_bf16.h>

typedef __attribute__((ext_vector_type(8))) short bf16x8;
typedef __attribute__((ext_vector_type(8))) unsigned short u16x8;
typedef __attribute__((ext_vector_type(4))) float f32x4;

#define NEG_INF (-__builtin_inff())
#define SPLIT 8

static __device__ __forceinline__ unsigned short f2bf(float x) {
  union { float f; unsigned u; } v; v.f = x;
  unsigned r = (v.u + 0x7fffu + ((v.u >> 16) & 1u)) >> 16;
  return (unsigned short)r;
}

// ---- KV f32 -> bf16 row-major + bf16 blocked-transpose kvt[blk][64][32];
// ---- also computes segment boundaries (fused): seg[b]=start, seg[8+b]=end ----
__global__ void prep_kv_kernel(const float* __restrict__ kv, const int* __restrict__ kvc,
                               unsigned short* __restrict__ kvb, unsigned short* __restrict__ kvt,
                               int* __restrict__ seg, int nkv) {
  __shared__ unsigned short tile[32][64];
  const int kv0 = blockIdx.x * 32;
  const int t = threadIdx.x;
  if (t < 32) {                      // fused segments logic, one row each
    int i = kv0 + t;
    if (i < nkv) {
      int c = kvc[i];
      int cp = (i == 0) ? -1 : kvc[i - 1];
      if (c != cp) {
        for (int b = cp + 1; b <= c; ++b) seg[b] = i;
        if (i == 0) for (int b = 0; b < c; ++b) seg[8 + b] = 0;
      }
      int cn = (i == nkv - 1) ? 8 : kvc[i + 1];
      if (c != cn) {
        for (int b = c; b < cn; ++b) seg[8 + b] = i + 1;
        if (i == nkv - 1) for (int b = c + 1; b < 8; ++b) seg[b] = nkv;
      }
    }
  }
  int r = (t * 8) >> 6;
  int c = (t * 8) & 63;
  const float4* src = (const float4*)(kv + (size_t)(kv0 + r) * 64 + c);
  float4 a = src[0], b = src[1];
  u16x8 v;
  v[0] = f2bf(a.x); v[1] = f2bf(a.y); v[2] = f2bf(a.z); v[3] = f2bf(a.w);
  v[4] = f2bf(b.x); v[5] = f2bf(b.y); v[6] = f2bf(b.z); v[7] = f2bf(b.w);
  *(u16x8*)&tile[r][c] = v;
  *(u16x8*)(kvb + (size_t)(kv0 + r) * 64 + c) = v;
  __syncthreads();
  int d = t & 63;                    // feature
  int k0 = (t >> 6) * 8;             // local kv 0/8/16/24
  u16x8 w;
#pragma unroll
  for (int j = 0; j < 8; ++j) w[j] = tile[k0 + j][d];
  // blocked transpose: kvt[blk][d][klocal], 4KB per 32-row block
  *(u16x8*)(kvt + (size_t)blockIdx.x * 2048 + d * 32 + k0) = w;
}

// ---- main: 8 waves per 16-query tile; each wave takes 1/8 of the KV segment ----
__global__ __launch_bounds__(512, 4) void attn_kernel(
    const float* __restrict__ qf,            // [n1][64] f32
    const unsigned short* __restrict__ kvb,  // [n2][64] bf16
    const unsigned short* __restrict__ kvt,  // [n2/32][64][32] bf16
    const int* __restrict__ qc, const int* __restrict__ kvc,
    const int* __restrict__ seg,
    float* __restrict__ out, int n2)
{
  __shared__ float p_lds[SPLIT][16][36];
  __shared__ float macc[SPLIT][16][68];
  __shared__ float mml[SPLIT][16];
  __shared__ float mll[SPLIT][16];

  const int q0 = blockIdx.x * 16;
  const int w = threadIdx.x >> 6;
  const int lane = threadIdx.x & 63;
  const int q16 = lane & 15;
  const int g = lane >> 4;

  // Q A-fragments straight from f32: A[i=q16][k=32*kb + 8*g + j]
  bf16x8 aq0, aq1;
  {
    const float* qrow = qf + (size_t)(q0 + q16) * 64 + g * 8;
    float4 x0 = *(const float4*)(qrow);
    float4 x1 = *(const float4*)(qrow + 4);
    float4 x2 = *(const float4*)(qrow + 32);
    float4 x3 = *(const float4*)(qrow + 36);
    aq0[0]=(short)f2bf(x0.x); aq0[1]=(short)f2bf(x0.y); aq0[2]=(short)f2bf(x0.z); aq0[3]=(short)f2bf(x0.w);
    aq0[4]=(short)f2bf(x1.x); aq0[5]=(short)f2bf(x1.y); aq0[6]=(short)f2bf(x1.z); aq0[7]=(short)f2bf(x1.w);
    aq1[0]=(short)f2bf(x2.x); aq1[1]=(short)f2bf(x2.y); aq1[2]=(short)f2bf(x2.z); aq1[3]=(short)f2bf(x2.w);
    aq1[4]=(short)f2bf(x3.x); aq1[5]=(short)f2bf(x3.y); aq1[6]=(short)f2bf(x3.z); aq1[7]=(short)f2bf(x3.w);
  }

  int qcoor[4];
#pragma unroll
  for (int r = 0; r < 4; ++r) qcoor[r] = qc[q0 + g * 4 + r];

  const int bfirst = qc[q0];
  const int blast  = qc[q0 + 15];
  const int kv_lo = seg[bfirst];
  const int kv_hi = seg[8 + blast];
  const bool uniformb = (bfirst == blast);
  const int base = kv_lo & ~31;
  const int nblk = (kv_hi - base + 31) >> 5;
  const int b0 = (nblk * w) / SPLIT;
  const int b1 = (nblk * (w + 1)) / SPLIT;

  f32x4 acc0 = {0,0,0,0}, acc1 = {0,0,0,0}, acc2 = {0,0,0,0}, acc3 = {0,0,0,0};
  float m[4] = {NEG_INF, NEG_INF, NEG_INF, NEG_INF};
  float l[4] = {0, 0, 0, 0};
  const float scale = 0.125f;  // 1/sqrt(64)

  // prologue: K fragments for first block
  bf16x8 ck0, ck1, ck2, ck3;
  if (b0 < b1) {
    const int kv0 = base + b0 * 32;
    const unsigned short* kr0 = kvb + (size_t)(kv0 + q16) * 64 + g * 8;
    const unsigned short* kr1 = kvb + (size_t)(kv0 + 16 + q16) * 64 + g * 8;
    ck0 = *(const bf16x8*)(kr0);
    ck1 = *(const bf16x8*)(kr0 + 32);
    ck2 = *(const bf16x8*)(kr1);
    ck3 = *(const bf16x8*)(kr1 + 32);
  }

  for (int b = b0; b < b1; ++b) {
    const int kv0 = base + b * 32;
    // V fragments for current block (blocked layout: one hot 4KB region)
    const unsigned short* vb = kvt + (size_t)(kv0 >> 5) * 2048 + q16 * 32 + g * 8;
    bf16x8 bv0 = *(const bf16x8*)(vb);
    bf16x8 bv1 = *(const bf16x8*)(vb + 512);
    bf16x8 bv2 = *(const bf16x8*)(vb + 1024);
    bf16x8 bv3 = *(const bf16x8*)(vb + 1536);
    const int kvc0 = kvc[kv0 + q16];
    const int kvc1 = kvc[kv0 + 16 + q16];

    f32x4 s0 = {0,0,0,0}, s1 = {0,0,0,0};
    s0 = __builtin_amdgcn_mfma_f32_16x16x32_bf16(aq0, ck0, s0, 0, 0, 0);
    s0 = __builtin_amdgcn_mfma_f32_16x16x32_bf16(aq1, ck1, s0, 0, 0, 0);
    s1 = __builtin_amdgcn_mfma_f32_16x16x32_bf16(aq0, ck2, s1, 0, 0, 0);
    s1 = __builtin_amdgcn_mfma_f32_16x16x32_bf16(aq1, ck3, s1, 0, 0, 0);

    // prefetch next block's K fragments (dummy-reload last block: uniform, no branch)
    {
      const int bn = (b + 1 < b1) ? b + 1 : b;
      const int kvn = base + bn * 32;
      const unsigned short* nr0 = kvb + (size_t)(kvn + q16) * 64 + g * 8;
      const unsigned short* nr1 = kvb + (size_t)(kvn + 16 + q16) * 64 + g * 8;
      ck0 = *(const bf16x8*)(nr0);
      ck1 = *(const bf16x8*)(nr0 + 32);
      ck2 = *(const bf16x8*)(nr1);
      ck3 = *(const bf16x8*)(nr1 + 32);
    }

    const bool full = uniformb && (kv0 >= kv_lo) && (kv0 + 32 <= kv_hi);
    float v0[4], v1[4];
    if (full) {
#pragma unroll
      for (int r = 0; r < 4; ++r) { v0[r] = s0[r] * scale; v1[r] = s1[r] * scale; }
    } else {
#pragma unroll
      for (int r = 0; r < 4; ++r) {
        v0[r] = (qcoor[r] == kvc0) ? s0[r] * scale : NEG_INF;
        v1[r] = (qcoor[r] == kvc1) ? s1[r] * scale : NEG_INF;
      }
    }

    float p0[4], p1[4], fr[4];
#pragma unroll
    for (int r = 0; r < 4; ++r) {
      float t = fmaxf(v0[r], v1[r]);
      t = fmaxf(t, __shfl_xor(t, 1));
      t = fmaxf(t, __shfl_xor(t, 2));
      t = fmaxf(t, __shfl_xor(t, 4));
      t = fmaxf(t, __shfl_xor(t, 8));
      float mn = fmaxf(m[r], t);
      float f, e0, e1;
      if (mn == NEG_INF) { f = 1.0f; e0 = 0.0f; e1 = 0.0f; }
      else {
        f  = __expf(m[r] - mn);
        e0 = __expf(v0[r] - mn);
        e1 = __expf(v1[r] - mn);
      }
      l[r] = l[r] * f + e0 + e1;   // per-lane partial, reduced once at the end
      m[r] = mn;
      p0[r] = e0; p1[r] = e1; fr[r] = f;
    }
#pragma unroll
    for (int r = 0; r < 4; ++r) {
      acc0[r] *= fr[r]; acc1[r] *= fr[r]; acc2[r] *= fr[r]; acc3[r] *= fr[r];
    }
    // P (16x32 f32) through LDS: write D-layout, read A-layout (same wave, no barrier)
#pragma unroll
    for (int r = 0; r < 4; ++r) {
      p_lds[w][g * 4 + r][q16] = p0[r];
      p_lds[w][g * 4 + r][16 + q16] = p1[r];
    }
    float pv[8];
    *(f32x4*)&pv[0] = *(const f32x4*)&p_lds[w][q16][g * 8];
    *(f32x4*)&pv[4] = *(const f32x4*)&p_lds[w][q16][g * 8 + 4];
    bf16x8 pa;
#pragma unroll
    for (int j = 0; j < 8; ++j) pa[j] = (short)f2bf(pv[j]);

    acc0 = __builtin_amdgcn_mfma_f32_16x16x32_bf16(pa, bv0, acc0, 0, 0, 0);
    acc1 = __builtin_amdgcn_mfma_f32_16x16x32_bf16(pa, bv1, acc1, 0, 0, 0);
    acc2 = __builtin_amdgcn_mfma_f32_16x16x32_bf16(pa, bv2, acc2, 0, 0, 0);
    acc3 = __builtin_amdgcn_mfma_f32_16x16x32_bf16(pa, bv3, acc3, 0, 0, 0);
  }

  // finalize per-wave partials
  float lsum[4];
#pragma unroll
  for (int r = 0; r < 4; ++r) {
    float sm = l[r];
    sm += __shfl_xor(sm, 1);
    sm += __shfl_xor(sm, 2);
    sm += __shfl_xor(sm, 4);
    sm += __shfl_xor(sm, 8);
    lsum[r] = sm;
  }
#pragma unroll
  for (int r = 0; r < 4; ++r) {
    const int row = g * 4 + r;
    macc[w][row][q16]      = acc0[r];
    macc[w][row][16 + q16] = acc1[r];
    macc[w][row][32 + q16] = acc2[r];
    macc[w][row][48 + q16] = acc3[r];
    if (q16 == 0) { mml[w][row] = m[r]; mll[w][row] = lsum[r]; }
  }
  __syncthreads();

  // merge SPLIT partials: 512 threads over 16 rows x 64 features (2 cols each)
  {
    const int t = threadIdx.x;
    const int i = t >> 5;
    const int c0 = (t & 31) * 2;
    float mstar = NEG_INF;
#pragma unroll
    for (int ww = 0; ww < SPLIT; ++ww) mstar = fmaxf(mstar, mml[ww][i]);
    float s[SPLIT];
    float L = 0.0f;
#pragma unroll
    for (int ww = 0; ww < SPLIT; ++ww) {
      float mw = mml[ww][i];
      s[ww] = (mw == NEG_INF) ? 0.0f : __expf(mw - mstar);
      L += s[ww] * mll[ww][i];
    }
    float inv = (L > 0.0f) ? 1.0f / L : 0.0f;
    float n0 = 0.0f, n1 = 0.0f;
#pragma unroll
    for (int ww = 0; ww < SPLIT; ++ww) {
      n0 += s[ww] * macc[ww][i][c0];
      n1 += s[ww] * macc[ww][i][c0 + 1];
    }
    float* o = out + (size_t)(q0 + i) * 64 + c0;
    o[0] = n0 * inv;
    o[1] = n1 * inv;
  }
}

extern "C" void kernel_launch(void* const* d_in, const int* in_sizes, int n_in,
                              void* d_out, int out_size, void* d_ws, size_t ws_size,
                              hipStream_t stream) {
  const float* q  = (const float*)d_in[0];
  const float* kv = (const float*)d_in[1];
  const int* qc   = (const int*)d_in[2];
  const int* kvc  = (const int*)d_in[3];
  float* out = (float*)d_out;

  const int C = 64;
  const int n1 = in_sizes[0] / C;   // 8192
  const int n2 = in_sizes[1] / C;   // 8192

  char* ws = (char*)d_ws;
  size_t off = 0;
  unsigned short* kvb = (unsigned short*)(ws + off); off += (size_t)n2 * C * 2;
  unsigned short* kvt = (unsigned short*)(ws + off); off += (size_t)n2 * C * 2;
  int* seg = (int*)(ws + off);

  prep_kv_kernel<<<n2 / 32, 256, 0, stream>>>(kv, kvc, kvb, kvt, seg, n2);
  attn_kernel<<<n1 / 16, 512, 0, stream>>>(q, kvb, kvt, qc, kvc, seg, out, n2);
}

// Round 4
// 32.189 us; speedup vs baseline: 3.4232x; 1.1292x over previous
//
#include <hip/hip_runtime.h>
#include <hip/hip_bf16.h>

typedef __attribute__((ext_vector_type(8))) short bf16x8;
typedef __attribute__((ext_vector_type(8))) unsigned short u16x8;
typedef __attribute__((ext_vector_type(4))) float f32x4;

#define NEG_INF (-__builtin_inff())
#define SPLIT 8

static __device__ __forceinline__ unsigned short f2bf(float x) {
  union { float f; unsigned u; } v; v.f = x;
  unsigned r = (v.u + 0x7fffu + ((v.u >> 16) & 1u)) >> 16;
  return (unsigned short)r;
}

// ---- KV f32 -> bf16 row-major + bf16 blocked-transpose kvt[blk][64][32];
// ---- also computes segment boundaries (fused): seg[b]=start, seg[8+b]=end ----
__global__ void prep_kv_kernel(const float* __restrict__ kv, const int* __restrict__ kvc,
                               unsigned short* __restrict__ kvb, unsigned short* __restrict__ kvt,
                               int* __restrict__ seg, int nkv) {
  __shared__ unsigned short tile[32][64];
  const int kv0 = blockIdx.x * 32;
  const int t = threadIdx.x;
  if (t < 32) {                      // fused segments logic, one row each
    int i = kv0 + t;
    if (i < nkv) {
      int c = kvc[i];
      int cp = (i == 0) ? -1 : kvc[i - 1];
      if (c != cp) {
        for (int b = cp + 1; b <= c; ++b) seg[b] = i;
        if (i == 0) for (int b = 0; b < c; ++b) seg[8 + b] = 0;
      }
      int cn = (i == nkv - 1) ? 8 : kvc[i + 1];
      if (c != cn) {
        for (int b = c; b < cn; ++b) seg[8 + b] = i + 1;
        if (i == nkv - 1) for (int b = c + 1; b < 8; ++b) seg[b] = nkv;
      }
    }
  }
  int r = (t * 8) >> 6;
  int c = (t * 8) & 63;
  const float4* src = (const float4*)(kv + (size_t)(kv0 + r) * 64 + c);
  float4 a = src[0], b = src[1];
  u16x8 v;
  v[0] = f2bf(a.x); v[1] = f2bf(a.y); v[2] = f2bf(a.z); v[3] = f2bf(a.w);
  v[4] = f2bf(b.x); v[5] = f2bf(b.y); v[6] = f2bf(b.z); v[7] = f2bf(b.w);
  *(u16x8*)&tile[r][c] = v;
  *(u16x8*)(kvb + (size_t)(kv0 + r) * 64 + c) = v;
  __syncthreads();
  int d = t & 63;                    // feature
  int k0 = (t >> 6) * 8;             // local kv 0/8/16/24
  u16x8 w;
#pragma unroll
  for (int j = 0; j < 8; ++j) w[j] = tile[k0 + j][d];
  // blocked transpose: kvt[blk][d][klocal], 4KB per 32-row block
  *(u16x8*)(kvt + (size_t)blockIdx.x * 2048 + d * 32 + k0) = w;
}

// ---- main: 8 waves per 16-query tile; swapped QK^T (S^T = K·Q), row-permuted
// ---- K frags so P^T lands directly in the PV B-fragment layout (no LDS/shuffle) ----
__global__ __launch_bounds__(512, 4) void attn_kernel(
    const float* __restrict__ qf,            // [n1][64] f32
    const unsigned short* __restrict__ kvb,  // [n2][64] bf16
    const unsigned short* __restrict__ kvt,  // [n2/32][64][32] bf16
    const int* __restrict__ qc,
    const int* __restrict__ seg,
    float* __restrict__ out, int n2)
{
  __shared__ float macc[SPLIT][16][68];
  __shared__ float mml[SPLIT][16];
  __shared__ float mll[SPLIT][16];

  const int q0 = blockIdx.x * 16;
  const int w = threadIdx.x >> 6;
  const int lane = threadIdx.x & 63;
  const int q16 = lane & 15;
  const int g = lane >> 4;
  const int g8 = g * 8;

  // Q B-fragments (scale 0.125 folded in; exact pow2): B[feat=8g+j][q=q16]
  bf16x8 qf0, qf1;
  {
    const float* qrow = qf + (size_t)(q0 + q16) * 64 + g8;
    float4 x0 = *(const float4*)(qrow);
    float4 x1 = *(const float4*)(qrow + 4);
    float4 x2 = *(const float4*)(qrow + 32);
    float4 x3 = *(const float4*)(qrow + 36);
    qf0[0]=(short)f2bf(x0.x*0.125f); qf0[1]=(short)f2bf(x0.y*0.125f);
    qf0[2]=(short)f2bf(x0.z*0.125f); qf0[3]=(short)f2bf(x0.w*0.125f);
    qf0[4]=(short)f2bf(x1.x*0.125f); qf0[5]=(short)f2bf(x1.y*0.125f);
    qf0[6]=(short)f2bf(x1.z*0.125f); qf0[7]=(short)f2bf(x1.w*0.125f);
    qf1[0]=(short)f2bf(x2.x*0.125f); qf1[1]=(short)f2bf(x2.y*0.125f);
    qf1[2]=(short)f2bf(x2.z*0.125f); qf1[3]=(short)f2bf(x2.w*0.125f);
    qf1[4]=(short)f2bf(x3.x*0.125f); qf1[5]=(short)f2bf(x3.y*0.125f);
    qf1[6]=(short)f2bf(x3.z*0.125f); qf1[7]=(short)f2bf(x3.w*0.125f);
  }

  // per-lane segment bounds for this lane's q-row
  const int myb = qc[q0 + q16];
  const int lo_q = seg[myb];
  const int hi_q = seg[8 + myb];

  const int bfirst = qc[q0];
  const int blast  = qc[q0 + 15];
  const int kv_lo = seg[bfirst];
  const int kv_hi = seg[8 + blast];
  const bool uniformb = (bfirst == blast);
  const int base = kv_lo & ~63;
  const int nblk = (kv_hi - base + 63) >> 6;
  const int b0 = (nblk * w) / SPLIT;
  const int b1 = (nblk * (w + 1)) / SPLIT;

  // K-row permutation offset: row(s) = kv0 + soff[s] + rowoff, rowoff = 8*(q16>>2)+(q16&3)
  const int rowoff = ((q16 >> 2) << 3) + (q16 & 3);

  f32x4 acc0 = {0,0,0,0}, acc1 = {0,0,0,0}, acc2 = {0,0,0,0}, acc3 = {0,0,0,0};
  float m = NEG_INF;
  float l = 0.0f;

  for (int b = b0; b < b1; ++b) {
    const int kv0 = base + b * 64;
    // K A-frags, row-permuted (sigma): 8 x b128
    const unsigned short* kb = kvb + (((size_t)(kv0 + rowoff)) << 6) + g8;
    bf16x8 kf00 = *(const bf16x8*)(kb);
    bf16x8 kf01 = *(const bf16x8*)(kb + 32);
    bf16x8 kf10 = *(const bf16x8*)(kb + 256);          // soff=4 rows
    bf16x8 kf11 = *(const bf16x8*)(kb + 256 + 32);
    bf16x8 kf20 = *(const bf16x8*)(kb + 2048);         // soff=32 rows
    bf16x8 kf21 = *(const bf16x8*)(kb + 2048 + 32);
    bf16x8 kf30 = *(const bf16x8*)(kb + 2304);         // soff=36 rows
    bf16x8 kf31 = *(const bf16x8*)(kb + 2304 + 32);
    // V^T A-frags from blocked kvt: 8 x b128
    const unsigned short* vb0 = kvt + (((size_t)kv0 >> 5) << 11) + q16 * 32 + g8;
    bf16x8 vf00 = *(const bf16x8*)(vb0);
    bf16x8 vf10 = *(const bf16x8*)(vb0 + 512);
    bf16x8 vf20 = *(const bf16x8*)(vb0 + 1024);
    bf16x8 vf30 = *(const bf16x8*)(vb0 + 1536);
    bf16x8 vf01 = *(const bf16x8*)(vb0 + 2048);
    bf16x8 vf11 = *(const bf16x8*)(vb0 + 2048 + 512);
    bf16x8 vf21 = *(const bf16x8*)(vb0 + 2048 + 1024);
    bf16x8 vf31 = *(const bf16x8*)(vb0 + 2048 + 1536);

    // swapped QK^T: sT[s] row = kv-local (permuted), col = q16
    f32x4 z = {0,0,0,0};
    f32x4 sT0 = __builtin_amdgcn_mfma_f32_16x16x32_bf16(kf00, qf0, z, 0, 0, 0);
    sT0 = __builtin_amdgcn_mfma_f32_16x16x32_bf16(kf01, qf1, sT0, 0, 0, 0);
    f32x4 sT1 = __builtin_amdgcn_mfma_f32_16x16x32_bf16(kf10, qf0, z, 0, 0, 0);
    sT1 = __builtin_amdgcn_mfma_f32_16x16x32_bf16(kf11, qf1, sT1, 0, 0, 0);
    f32x4 sT2 = __builtin_amdgcn_mfma_f32_16x16x32_bf16(kf20, qf0, z, 0, 0, 0);
    sT2 = __builtin_amdgcn_mfma_f32_16x16x32_bf16(kf21, qf1, sT2, 0, 0, 0);
    f32x4 sT3 = __builtin_amdgcn_mfma_f32_16x16x32_bf16(kf30, qf0, z, 0, 0, 0);
    sT3 = __builtin_amdgcn_mfma_f32_16x16x32_bf16(kf31, qf1, sT3, 0, 0, 0);

    // kv index of element (s,r): kv0 + soff[s] + 8g + r; v[s*4+r] = masked score
    float v[16];
    const bool full = uniformb && (kv0 >= kv_lo) && (kv0 + 64 <= kv_hi);
    if (full) {
#pragma unroll
      for (int r = 0; r < 4; ++r) {
        v[r] = sT0[r]; v[4 + r] = sT1[r]; v[8 + r] = sT2[r]; v[12 + r] = sT3[r];
      }
    } else {
      const int kb0 = kv0 + g8;
#pragma unroll
      for (int r = 0; r < 4; ++r) {
        int k0 = kb0 + r;
        v[r]      = (k0      >= lo_q && k0      < hi_q) ? sT0[r] : NEG_INF;
        v[4 + r]  = (k0 + 4  >= lo_q && k0 + 4  < hi_q) ? sT1[r] : NEG_INF;
        v[8 + r]  = (k0 + 32 >= lo_q && k0 + 32 < hi_q) ? sT2[r] : NEG_INF;
        v[12 + r] = (k0 + 36 >= lo_q && k0 + 36 < hi_q) ? sT3[r] : NEG_INF;
      }
    }

    // online softmax, one scalar per lane (lane owns q-row q16)
    float t0 = fmaxf(fmaxf(v[0], v[1]), fmaxf(v[2], v[3]));
    float t1 = fmaxf(fmaxf(v[4], v[5]), fmaxf(v[6], v[7]));
    float t2 = fmaxf(fmaxf(v[8], v[9]), fmaxf(v[10], v[11]));
    float t3 = fmaxf(fmaxf(v[12], v[13]), fmaxf(v[14], v[15]));
    float t = fmaxf(fmaxf(t0, t1), fmaxf(t2, t3));
    t = fmaxf(t, __shfl_xor(t, 16));
    t = fmaxf(t, __shfl_xor(t, 32));
    float mn = fmaxf(m, t);
    float f = (mn == NEG_INF) ? 1.0f : __expf(m - mn);
    float e[16];
#pragma unroll
    for (int i = 0; i < 16; ++i)
      e[i] = (v[i] == NEG_INF) ? 0.0f : __expf(v[i] - mn);
    float s0 = (e[0] + e[1]) + (e[2] + e[3]);
    float s1 = (e[4] + e[5]) + (e[6] + e[7]);
    float s2 = (e[8] + e[9]) + (e[10] + e[11]);
    float s3 = (e[12] + e[13]) + (e[14] + e[15]);
    l = l * f + ((s0 + s1) + (s2 + s3));
    m = mn;
#pragma unroll
    for (int r = 0; r < 4; ++r) {
      acc0[r] *= f; acc1[r] *= f; acc2[r] *= f; acc3[r] *= f;
    }

    // P^T already in B-frag layout thanks to the row permutation:
    bf16x8 pa0, pa1;
#pragma unroll
    for (int j = 0; j < 8; ++j) {
      pa0[j] = (short)f2bf(e[j]);
      pa1[j] = (short)f2bf(e[8 + j]);
    }

    acc0 = __builtin_amdgcn_mfma_f32_16x16x32_bf16(vf00, pa0, acc0, 0, 0, 0);
    acc1 = __builtin_amdgcn_mfma_f32_16x16x32_bf16(vf10, pa0, acc1, 0, 0, 0);
    acc2 = __builtin_amdgcn_mfma_f32_16x16x32_bf16(vf20, pa0, acc2, 0, 0, 0);
    acc3 = __builtin_amdgcn_mfma_f32_16x16x32_bf16(vf30, pa0, acc3, 0, 0, 0);
    acc0 = __builtin_amdgcn_mfma_f32_16x16x32_bf16(vf01, pa1, acc0, 0, 0, 0);
    acc1 = __builtin_amdgcn_mfma_f32_16x16x32_bf16(vf11, pa1, acc1, 0, 0, 0);
    acc2 = __builtin_amdgcn_mfma_f32_16x16x32_bf16(vf21, pa1, acc2, 0, 0, 0);
    acc3 = __builtin_amdgcn_mfma_f32_16x16x32_bf16(vf31, pa1, acc3, 0, 0, 0);
  }

  // cross-g reduce of l (m already uniform across g)
  l += __shfl_xor(l, 16);
  l += __shfl_xor(l, 32);

  // write per-wave partials: macc[w][q][d]
#pragma unroll
  for (int r = 0; r < 4; ++r) {
    macc[w][q16][0  + g * 4 + r] = acc0[r];
    macc[w][q16][16 + g * 4 + r] = acc1[r];
    macc[w][q16][32 + g * 4 + r] = acc2[r];
    macc[w][q16][48 + g * 4 + r] = acc3[r];
  }
  if (g == 0) { mml[w][q16] = m; mll[w][q16] = l; }
  __syncthreads();

  // merge SPLIT partials: 512 threads over 16 rows x 64 features (2 cols each)
  {
    const int t = threadIdx.x;
    const int i = t >> 5;
    const int c0 = (t & 31) * 2;
    float mstar = NEG_INF;
#pragma unroll
    for (int ww = 0; ww < SPLIT; ++ww) mstar = fmaxf(mstar, mml[ww][i]);
    float s[SPLIT];
    float L = 0.0f;
#pragma unroll
    for (int ww = 0; ww < SPLIT; ++ww) {
      float mw = mml[ww][i];
      s[ww] = (mw == NEG_INF) ? 0.0f : __expf(mw - mstar);
      L += s[ww] * mll[ww][i];
    }
    float inv = (L > 0.0f) ? 1.0f / L : 0.0f;
    float n0 = 0.0f, n1 = 0.0f;
#pragma unroll
    for (int ww = 0; ww < SPLIT; ++ww) {
      n0 += s[ww] * macc[ww][i][c0];
      n1 += s[ww] * macc[ww][i][c0 + 1];
    }
    float* o = out + (size_t)(q0 + i) * 64 + c0;
    o[0] = n0 * inv;
    o[1] = n1 * inv;
  }
}

extern "C" void kernel_launch(void* const* d_in, const int* in_sizes, int n_in,
                              void* d_out, int out_size, void* d_ws, size_t ws_size,
                              hipStream_t stream) {
  const float* q  = (const float*)d_in[0];
  const float* kv = (const float*)d_in[1];
  const int* qc   = (const int*)d_in[2];
  const int* kvc  = (const int*)d_in[3];
  float* out = (float*)d_out;

  const int C = 64;
  const int n1 = in_sizes[0] / C;   // 8192
  const int n2 = in_sizes[1] / C;   // 8192

  char* ws = (char*)d_ws;
  size_t off = 0;
  unsigned short* kvb = (unsigned short*)(ws + off); off += (size_t)n2 * C * 2;
  unsigned short* kvt = (unsigned short*)(ws + off); off += (size_t)n2 * C * 2;
  int* seg = (int*)(ws + off);

  prep_kv_kernel<<<n2 / 32, 256, 0, stream>>>(kv, kvc, kvb, kvt, seg, n2);
  attn_kernel<<<n1 / 16, 512, 0, stream>>>(q, kvb, kvt, qc, seg, out, n2);
}

// Round 5
// 30.400 us; speedup vs baseline: 3.6246x; 1.0588x over previous
//
#include <hip/hip_runtime.h>
#include <hip/hip_bf16.h>

typedef __attribute__((ext_vector_type(8))) short bf16x8;
typedef __attribute__((ext_vector_type(8))) unsigned short u16x8;
typedef __attribute__((ext_vector_type(4))) float f32x4;

#define NEG_INF (-__builtin_inff())
#define SPLIT 4

static __device__ __forceinline__ unsigned short f2bf(float x) {
  union { float f; unsigned u; } v; v.f = x;
  unsigned r = (v.u + 0x7fffu + ((v.u >> 16) & 1u)) >> 16;
  return (unsigned short)r;
}

// ---- KV f32 -> bf16 row-major + bf16 blocked-transpose kvt[blk][64][32];
// ---- also computes segment boundaries (fused): seg[b]=start, seg[8+b]=end ----
__global__ void prep_kv_kernel(const float* __restrict__ kv, const int* __restrict__ kvc,
                               unsigned short* __restrict__ kvb, unsigned short* __restrict__ kvt,
                               int* __restrict__ seg, int nkv) {
  __shared__ unsigned short tile[32][64];
  const int kv0 = blockIdx.x * 32;
  const int t = threadIdx.x;
  if (t < 32) {                      // fused segments logic, one row each
    int i = kv0 + t;
    if (i < nkv) {
      int c = kvc[i];
      int cp = (i == 0) ? -1 : kvc[i - 1];
      if (c != cp) {
        for (int b = cp + 1; b <= c; ++b) seg[b] = i;
        if (i == 0) for (int b = 0; b < c; ++b) seg[8 + b] = 0;
      }
      int cn = (i == nkv - 1) ? 8 : kvc[i + 1];
      if (c != cn) {
        for (int b = c; b < cn; ++b) seg[8 + b] = i + 1;
        if (i == nkv - 1) for (int b = c + 1; b < 8; ++b) seg[b] = nkv;
      }
    }
  }
  int r = (t * 8) >> 6;
  int c = (t * 8) & 63;
  const float4* src = (const float4*)(kv + (size_t)(kv0 + r) * 64 + c);
  float4 a = src[0], b = src[1];
  u16x8 v;
  v[0] = f2bf(a.x); v[1] = f2bf(a.y); v[2] = f2bf(a.z); v[3] = f2bf(a.w);
  v[4] = f2bf(b.x); v[5] = f2bf(b.y); v[6] = f2bf(b.z); v[7] = f2bf(b.w);
  *(u16x8*)&tile[r][c] = v;
  *(u16x8*)(kvb + (size_t)(kv0 + r) * 64 + c) = v;
  __syncthreads();
  int d = t & 63;                    // feature
  int k0 = (t >> 6) * 8;             // local kv 0/8/16/24
  u16x8 w;
#pragma unroll
  for (int j = 0; j < 8; ++j) w[j] = tile[k0 + j][d];
  // blocked transpose: kvt[blk][d][klocal], 4KB per 32-row block
  *(u16x8*)(kvt + (size_t)blockIdx.x * 2048 + d * 32 + k0) = w;
}

// K fragments for block at kv index kvx, row-permuted (ping-pong set P)
#define LOADK(P, kvx)                                                          \
  {                                                                            \
    const unsigned short* kb_ = kvb + (((size_t)((kvx) + rowoff)) << 6) + g8;  \
    k##P##0 = *(const bf16x8*)(kb_);                                           \
    k##P##1 = *(const bf16x8*)(kb_ + 32);                                      \
    k##P##2 = *(const bf16x8*)(kb_ + 256);                                     \
    k##P##3 = *(const bf16x8*)(kb_ + 256 + 32);                                \
  }

#define COMPUTE(P, kvx)                                                        \
  {                                                                            \
    const int kv0_ = (kvx);                                                    \
    const unsigned short* vb_ = kvt + (((size_t)kv0_ >> 5) << 11) + q16 * 32 + g8; \
    bf16x8 vf0_ = *(const bf16x8*)(vb_);                                       \
    bf16x8 vf1_ = *(const bf16x8*)(vb_ + 512);                                 \
    bf16x8 vf2_ = *(const bf16x8*)(vb_ + 1024);                                \
    bf16x8 vf3_ = *(const bf16x8*)(vb_ + 1536);                                \
    f32x4 z_ = {0, 0, 0, 0};                                                   \
    __builtin_amdgcn_s_setprio(1);                                             \
    f32x4 sT0 = __builtin_amdgcn_mfma_f32_16x16x32_bf16(k##P##0, qf0, z_, 0, 0, 0); \
    sT0 = __builtin_amdgcn_mfma_f32_16x16x32_bf16(k##P##1, qf1, sT0, 0, 0, 0); \
    f32x4 sT1 = __builtin_amdgcn_mfma_f32_16x16x32_bf16(k##P##2, qf0, z_, 0, 0, 0); \
    sT1 = __builtin_amdgcn_mfma_f32_16x16x32_bf16(k##P##3, qf1, sT1, 0, 0, 0); \
    __builtin_amdgcn_s_setprio(0);                                             \
    float v_[8];                                                               \
    const bool full_ = uniformb && (kv0_ >= kv_lo) && (kv0_ + 32 <= kv_hi);    \
    if (full_) {                                                               \
      _Pragma("unroll") for (int r = 0; r < 4; ++r) {                          \
        v_[r] = sT0[r];                                                        \
        v_[4 + r] = sT1[r];                                                    \
      }                                                                        \
    } else {                                                                   \
      const int k0_ = kv0_ + g8;                                               \
      _Pragma("unroll") for (int r = 0; r < 4; ++r) {                          \
        v_[r]     = (k0_ + r     >= lo_q && k0_ + r     < hi_q) ? sT0[r] : NEG_INF; \
        v_[4 + r] = (k0_ + r + 4 >= lo_q && k0_ + r + 4 < hi_q) ? sT1[r] : NEG_INF; \
      }                                                                        \
    }                                                                          \
    float t_ = fmaxf(fmaxf(fmaxf(v_[0], v_[1]), fmaxf(v_[2], v_[3])),          \
                     fmaxf(fmaxf(v_[4], v_[5]), fmaxf(v_[6], v_[7])));         \
    t_ = fmaxf(t_, __shfl_xor(t_, 16));                                        \
    t_ = fmaxf(t_, __shfl_xor(t_, 32));                                        \
    float mn_ = fmaxf(m, t_);                                                  \
    float f_ = (mn_ == NEG_INF) ? 1.0f : __expf(m - mn_);                      \
    float e_[8];                                                               \
    _Pragma("unroll") for (int i = 0; i < 8; ++i)                              \
        e_[i] = (v_[i] == NEG_INF) ? 0.0f : __expf(v_[i] - mn_);               \
    l = l * f_ + (((e_[0] + e_[1]) + (e_[2] + e_[3])) +                        \
                  ((e_[4] + e_[5]) + (e_[6] + e_[7])));                        \
    m = mn_;                                                                   \
    _Pragma("unroll") for (int r = 0; r < 4; ++r) {                            \
      acc0[r] *= f_; acc1[r] *= f_; acc2[r] *= f_; acc3[r] *= f_;              \
    }                                                                          \
    bf16x8 pa_;                                                                \
    _Pragma("unroll") for (int j = 0; j < 8; ++j) pa_[j] = (short)f2bf(e_[j]); \
    __builtin_amdgcn_s_setprio(1);                                             \
    acc0 = __builtin_amdgcn_mfma_f32_16x16x32_bf16(vf0_, pa_, acc0, 0, 0, 0);  \
    acc1 = __builtin_amdgcn_mfma_f32_16x16x32_bf16(vf1_, pa_, acc1, 0, 0, 0);  \
    acc2 = __builtin_amdgcn_mfma_f32_16x16x32_bf16(vf2_, pa_, acc2, 0, 0, 0);  \
    acc3 = __builtin_amdgcn_mfma_f32_16x16x32_bf16(vf3_, pa_, acc3, 0, 0, 0);  \
    __builtin_amdgcn_s_setprio(0);                                             \
  }

// ---- main: 4 waves per 16-query tile; swapped QK^T (S^T = K.Q), row-permuted
// ---- K frags so P^T lands directly in the PV B-fragment layout (no LDS/shuffle) ----
__global__ __launch_bounds__(256, 4) void attn_kernel(
    const float* __restrict__ qf,            // [n1][64] f32
    const unsigned short* __restrict__ kvb,  // [n2][64] bf16
    const unsigned short* __restrict__ kvt,  // [n2/32][64][32] bf16
    const int* __restrict__ qc,
    const int* __restrict__ seg,
    float* __restrict__ out, int n2)
{
  __shared__ float macc[SPLIT][16][68];
  __shared__ float mml[SPLIT][16];
  __shared__ float mll[SPLIT][16];

  const int q0 = blockIdx.x * 16;
  const int w = threadIdx.x >> 6;          // 0..3
  const int lane = threadIdx.x & 63;
  const int q16 = lane & 15;
  const int g = lane >> 4;
  const int g8 = g * 8;

  // per-lane segment bounds for this lane's q-row (3 loads; rest via shfl)
  const int myb = qc[q0 + q16];
  const int lo_q = seg[myb];
  const int hi_q = seg[8 + myb];
  const int bfirst = __shfl(myb, 0);
  const int blast  = __shfl(myb, 15);
  const int kv_lo  = __shfl(lo_q, 0);
  const int kv_hi  = __shfl(hi_q, 15);
  const bool uniformb = (bfirst == blast);

  // Q B-fragments (scale 0.125 folded in; exact pow2): B[feat=8g+j][q=q16]
  bf16x8 qf0, qf1;
  {
    const float* qrow = qf + (size_t)(q0 + q16) * 64 + g8;
    float4 x0 = *(const float4*)(qrow);
    float4 x1 = *(const float4*)(qrow + 4);
    float4 x2 = *(const float4*)(qrow + 32);
    float4 x3 = *(const float4*)(qrow + 36);
    qf0[0]=(short)f2bf(x0.x*0.125f); qf0[1]=(short)f2bf(x0.y*0.125f);
    qf0[2]=(short)f2bf(x0.z*0.125f); qf0[3]=(short)f2bf(x0.w*0.125f);
    qf0[4]=(short)f2bf(x1.x*0.125f); qf0[5]=(short)f2bf(x1.y*0.125f);
    qf0[6]=(short)f2bf(x1.z*0.125f); qf0[7]=(short)f2bf(x1.w*0.125f);
    qf1[0]=(short)f2bf(x2.x*0.125f); qf1[1]=(short)f2bf(x2.y*0.125f);
    qf1[2]=(short)f2bf(x2.z*0.125f); qf1[3]=(short)f2bf(x2.w*0.125f);
    qf1[4]=(short)f2bf(x3.x*0.125f); qf1[5]=(short)f2bf(x3.y*0.125f);
    qf1[6]=(short)f2bf(x3.z*0.125f); qf1[7]=(short)f2bf(x3.w*0.125f);
  }

  const int base = kv_lo & ~31;
  const int nblk = (kv_hi - base + 31) >> 5;
  const int b0 = (nblk * w) / SPLIT;
  const int b1 = (nblk * (w + 1)) / SPLIT;

  // K-row permutation: A row i (=q16) of sub-tile s reads kv row kv0 + 8*(i>>2)+(i&3) + 4s
  const int rowoff = ((q16 >> 2) << 3) + (q16 & 3);

  f32x4 acc0 = {0,0,0,0}, acc1 = {0,0,0,0}, acc2 = {0,0,0,0}, acc3 = {0,0,0,0};
  float m = NEG_INF;
  float l = 0.0f;

  bf16x8 kA0, kA1, kA2, kA3, kB0, kB1, kB2, kB3;
  int b = b0;
  if (b < b1) {
    LOADK(A, base + b * 32);
    while (true) {
      if (b + 1 < b1) LOADK(B, base + (b + 1) * 32);
      COMPUTE(A, base + b * 32);
      ++b; if (b >= b1) break;
      if (b + 1 < b1) LOADK(A, base + (b + 1) * 32);
      COMPUTE(B, base + b * 32);
      ++b; if (b >= b1) break;
    }
  }

  // cross-g reduce of l (m already uniform across g)
  l += __shfl_xor(l, 16);
  l += __shfl_xor(l, 32);

  // write per-wave partials: macc[w][q][d]
#pragma unroll
  for (int r = 0; r < 4; ++r) {
    macc[w][q16][0  + g * 4 + r] = acc0[r];
    macc[w][q16][16 + g * 4 + r] = acc1[r];
    macc[w][q16][32 + g * 4 + r] = acc2[r];
    macc[w][q16][48 + g * 4 + r] = acc3[r];
  }
  if (g == 0) { mml[w][q16] = m; mll[w][q16] = l; }
  __syncthreads();

  // merge SPLIT partials: 256 threads over 16 rows x 64 features (4 cols each)
  {
    const int t = threadIdx.x;
    const int i = t >> 4;
    const int c0 = (t & 15) * 4;
    float mstar = NEG_INF;
#pragma unroll
    for (int ww = 0; ww < SPLIT; ++ww) mstar = fmaxf(mstar, mml[ww][i]);
    float s[SPLIT];
    float L = 0.0f;
#pragma unroll
    for (int ww = 0; ww < SPLIT; ++ww) {
      float mw = mml[ww][i];
      s[ww] = (mw == NEG_INF) ? 0.0f : __expf(mw - mstar);
      L += s[ww] * mll[ww][i];
    }
    float inv = (L > 0.0f) ? 1.0f / L : 0.0f;
    f32x4 num = {0, 0, 0, 0};
#pragma unroll
    for (int ww = 0; ww < SPLIT; ++ww) {
      f32x4 a = *(const f32x4*)&macc[ww][i][c0];
      num[0] += s[ww] * a[0]; num[1] += s[ww] * a[1];
      num[2] += s[ww] * a[2]; num[3] += s[ww] * a[3];
    }
    float* o = out + (size_t)(q0 + i) * 64 + c0;
    o[0] = num[0] * inv; o[1] = num[1] * inv;
    o[2] = num[2] * inv; o[3] = num[3] * inv;
  }
}

extern "C" void kernel_launch(void* const* d_in, const int* in_sizes, int n_in,
                              void* d_out, int out_size, void* d_ws, size_t ws_size,
                              hipStream_t stream) {
  const float* q  = (const float*)d_in[0];
  const float* kv = (const float*)d_in[1];
  const int* qc   = (const int*)d_in[2];
  const int* kvc  = (const int*)d_in[3];
  float* out = (float*)d_out;

  const int C = 64;
  const int n1 = in_sizes[0] / C;   // 8192
  const int n2 = in_sizes[1] / C;   // 8192

  char* ws = (char*)d_ws;
  size_t off = 0;
  unsigned short* kvb = (unsigned short*)(ws + off); off += (size_t)n2 * C * 2;
  unsigned short* kvt = (unsigned short*)(ws + off); off += (size_t)n2 * C * 2;
  int* seg = (int*)(ws + off);

  prep_kv_kernel<<<n2 / 32, 256, 0, stream>>>(kv, kvc, kvb, kvt, seg, n2);
  attn_kernel<<<n1 / 16, 256, 0, stream>>>(q, kvb, kvt, qc, seg, out, n2);
}